// Round 8
// baseline (516.671 us; speedup 1.0000x reference)
//
#include <hip/hip_runtime.h>
#include <math.h>

#define DIMD    1024
#define MLPD    4096
#define DSTATE  16
#define DCONV   4
#define HALF    1024
#define DINNER  2048
#define DTRANK  64
#define BSZ     2
#define SEQ     2048
#define NTOK    (BSZ*SEQ)   // 4096
#define NCH     64
#define CL      (SEQ/NCH)   // 32

typedef short bf16x8 __attribute__((ext_vector_type(8)));
typedef float f32x4  __attribute__((ext_vector_type(4)));
typedef unsigned short u16;
typedef unsigned int   u32;

__device__ __forceinline__ u16 f2bf(float x) {
    union { float f; unsigned int u; } v; v.f = x;
    unsigned int r = (v.u + 0x7FFFu + ((v.u >> 16) & 1u)) >> 16;
    return (u16)r;
}
__device__ __forceinline__ float bf2f(u16 x) {
    union { unsigned int u; float f; } v; v.u = ((unsigned int)x) << 16;
    return v.f;
}

// ---------------- fused LN1 + weight f32->bf16 convert -------------------
#define SZ_WIN  (DINNER*DIMD)
#define SZ_WXP  (96*HALF)
#define SZ_WDT  (HALF*DTRANK)
#define SZ_WOUT (DIMD*DINNER)
#define SZ_WM1  (MLPD*DIMD)
#define SZ_WM2  (DIMD*MLPD)
#define SZ_TOT  (SZ_WIN+SZ_WXP+SZ_WDT+SZ_WOUT+SZ_WM1+SZ_WM2)
#define CVT_BLOCKS ((SZ_TOT + 255) / 256)

__global__ __launch_bounds__(256) void cvtln_kernel(
        const float* __restrict__ x, const float* __restrict__ g,
        const float* __restrict__ b, u16* __restrict__ xn_bf,
        const float* __restrict__ s0, u16* __restrict__ d0,
        const float* __restrict__ s1, u16* __restrict__ d1,
        const float* __restrict__ s2, u16* __restrict__ d2,
        const float* __restrict__ s3, u16* __restrict__ d3,
        const float* __restrict__ s4, u16* __restrict__ d4,
        const float* __restrict__ s5, u16* __restrict__ d5) {
    if (blockIdx.x >= NTOK) {
        int i = (blockIdx.x - NTOK) * 256 + threadIdx.x;
        if (i < SZ_WIN)  { d0[i] = f2bf(s0[i]); return; }  i -= SZ_WIN;
        if (i < SZ_WXP)  { d1[i] = f2bf(s1[i]); return; }  i -= SZ_WXP;
        if (i < SZ_WDT)  { d2[i] = f2bf(s2[i]); return; }  i -= SZ_WDT;
        if (i < SZ_WOUT) { d3[i] = f2bf(s3[i]); return; }  i -= SZ_WOUT;
        if (i < SZ_WM1)  { d4[i] = f2bf(s4[i]); return; }  i -= SZ_WM1;
        if (i < SZ_WM2)  { d5[i] = f2bf(s5[i]); }
        return;
    }
    __shared__ float sm[4];
    int row = blockIdx.x;
    int t = threadIdx.x;
    const float4* xr = (const float4*)(x + (size_t)row * DIMD);
    float4 v = xr[t];
    float s = v.x + v.y + v.z + v.w;
    for (int off = 32; off > 0; off >>= 1) s += __shfl_down(s, off, 64);
    if ((t & 63) == 0) sm[t >> 6] = s;
    __syncthreads();
    float mu = (sm[0] + sm[1] + sm[2] + sm[3]) * (1.0f / DIMD);
    float dx = v.x - mu, dy = v.y - mu, dz = v.z - mu, dw = v.w - mu;
    float ss = dx*dx + dy*dy + dz*dz + dw*dw;
    for (int off = 32; off > 0; off >>= 1) ss += __shfl_down(ss, off, 64);
    __syncthreads();
    if ((t & 63) == 0) sm[t >> 6] = ss;
    __syncthreads();
    float var = (sm[0] + sm[1] + sm[2] + sm[3]) * (1.0f / DIMD);
    float rs = rsqrtf(var + 1e-5f);
    float4 gv = ((const float4*)g)[t];
    float4 bv = ((const float4*)b)[t];
    u16* o = xn_bf + (size_t)row * DIMD + t * 4;
    o[0] = f2bf(dx * rs * gv.x + bv.x);
    o[1] = f2bf(dy * rs * gv.y + bv.y);
    o[2] = f2bf(dz * rs * gv.z + bv.z);
    o[3] = f2bf(dw * rs * gv.w + bv.w);
}

// ---------------- x_proj GEMM: 4 waves = 2 m-tiles x 2 K-halves ----------
__global__ __launch_bounds__(256) void gemm_small_kernel(
        const u16* __restrict__ A, int lda,
        const u16* __restrict__ W, int K, int N,
        float* __restrict__ Cf, u16* __restrict__ Cb) {
    __shared__ f32x4 red[2][64];
    int t = threadIdx.x;
    int w = t >> 6, lane = t & 63;
    int mt = w & 1, kh = w >> 1;
    int m0 = blockIdx.x * 32 + mt * 16;
    int n0 = blockIdx.y * 16;
    int r = lane & 15, quad = lane >> 4;
    int Kh = K >> 1;
    f32x4 acc = {0.f, 0.f, 0.f, 0.f};
    const u16* ap = A + (size_t)(m0 + r) * lda + kh * Kh + quad * 8;
    const u16* wp = W + (size_t)(n0 + r) * K   + kh * Kh + quad * 8;
    for (int k = 0; k < Kh; k += 32) {
        bf16x8 av = *(const bf16x8*)(ap + k);
        bf16x8 bv = *(const bf16x8*)(wp + k);
        acc = __builtin_amdgcn_mfma_f32_16x16x32_bf16(av, bv, acc, 0, 0, 0);
    }
    if (kh == 1) red[mt][lane] = acc;
    __syncthreads();
    if (kh == 0) {
        f32x4 o = red[mt][lane];
        int col = n0 + r;
        #pragma unroll
        for (int i = 0; i < 4; ++i) {
            int row = m0 + quad * 4 + i;
            size_t idx = (size_t)row * N + col;
            float v = acc[i] + o[i];
            Cf[idx] = v;
            Cb[idx] = f2bf(v);
        }
    }
}

// ---------------- big GEMM: A-direct registers, B via LDS dbuf ----------
// C[M,N] = A[M,K] * W[N,K]^T, bf16 in, f32 acc. M%128, N%TN, (K/KS)%64==0.
// 4 waves = 4 m-strips of 32 rows; each wave computes 32 x TN.
// A fragments: global->VGPR double-buffered (issued AFTER B staging so the
// barrier's vmcnt drain can leave them in flight). B tile: global_load_lds
// double-buffer with XOR swizzle (conflict-free, m136).
// EPI: 0 f32 | 1 bias+softplus f32 | 2 bias+gelu(tanh) bf16 | 3 +resid f32
//      4 bias+resid f32 | 5 plain bf16
template<int EPI, int TN, int KS>
__global__ __launch_bounds__(256) void gemm128_kernel(
        const u16* __restrict__ A, int lda, const u16* __restrict__ W,
        int K, int N,
        const float* __restrict__ bias, const float* __restrict__ resid,
        float* __restrict__ Cf, float* __restrict__ Cf2,
        u16* __restrict__ Cb) {
    constexpr int NW = TN / 16;       // n-frags per wave
    constexpr int NB = TN * 4 / 256;  // B staging instr per wave
    __shared__ u16 Bs0[TN * 32], Bs1[TN * 32];
    const int t = threadIdx.x;
    const int w = t >> 6;             // wave = m-strip
    const int lane = t & 63;
    const int r = lane & 15, quad = lane >> 4;
    const int m0 = blockIdx.x * 128;
    const int n0 = blockIdx.y * TN;
    const int Kloc = K / KS;
    const int kz = (KS == 2) ? blockIdx.z : 0;

    f32x4 acc[2][NW];
    #pragma unroll
    for (int mi = 0; mi < 2; ++mi)
        #pragma unroll
        for (int ni = 0; ni < NW; ++ni)
            acc[mi][ni] = (f32x4){0.f, 0.f, 0.f, 0.f};

    // A fragment pointers (2 frags/wave: rows w*32+mi*16+r)
    const u16* pA[2];
    #pragma unroll
    for (int mi = 0; mi < 2; ++mi)
        pA[mi] = A + (size_t)(m0 + w * 32 + mi * 16 + r) * lda
                   + (size_t)kz * Kloc + quad * 8;
    // B staging pointers (swizzled source)
    const u16* pb[NB];
    #pragma unroll
    for (int i = 0; i < NB; ++i) {
        int c = (i * 4 + w) * 64 + lane;
        int row = c >> 2;
        int q = (c & 3) ^ ((row >> 1) & 3);
        pb[i] = W + (size_t)(n0 + row) * K + (size_t)kz * Kloc + q * 8;
    }
    // B LDS read offsets (un-swizzle)
    const int qs = quad ^ ((r >> 1) & 3);
    int boff[NW];
    #pragma unroll
    for (int ni = 0; ni < NW; ++ni)
        boff[ni] = (ni * 16 + r) * 32 + qs * 8;

    auto stageB = [&](u16* __restrict__ Bd) {
        #pragma unroll
        for (int i = 0; i < NB; ++i) {
            __builtin_amdgcn_global_load_lds(
                (const __attribute__((address_space(1))) u32*)pb[i],
                (__attribute__((address_space(3))) u32*)(Bd + (i * 4 + w) * 512),
                16, 0, 0);
            pb[i] += 32;
        }
    };
    auto loadA = [&](bf16x8* dst) {
        #pragma unroll
        for (int mi = 0; mi < 2; ++mi) {
            dst[mi] = *(const bf16x8*)pA[mi];
            pA[mi] += 32;
        }
    };
    auto compute = [&](const bf16x8* a, const u16* __restrict__ Bb) {
        bf16x8 bfr[NW];
        #pragma unroll
        for (int ni = 0; ni < NW; ++ni) bfr[ni] = *(const bf16x8*)(Bb + boff[ni]);
        #pragma unroll
        for (int mi = 0; mi < 2; ++mi)
            #pragma unroll
            for (int ni = 0; ni < NW; ++ni)
                acc[mi][ni] = __builtin_amdgcn_mfma_f32_16x16x32_bf16(
                    a[mi], bfr[ni], acc[mi][ni], 0, 0, 0);
    };

    bf16x8 aC[2], aN[2];
    stageB(Bs0);
    loadA(aC);
    for (int k0 = 0; k0 < Kloc; k0 += 64) {
        __syncthreads();                 // Bs0 staged; prev Bs0 reads done
        if (k0 + 32 < Kloc) { stageB(Bs1); loadA(aN); }
        compute(aC, Bs0);
        __syncthreads();                 // Bs1 staged; Bs0 reads done
        if (k0 + 64 < Kloc) { stageB(Bs0); loadA(aC); }
        compute(aN, Bs1);
    }

    float* Cfo = (KS == 2 && kz) ? Cf2 : Cf;
    #pragma unroll
    for (int mi = 0; mi < 2; ++mi) {
        #pragma unroll
        for (int i = 0; i < 4; ++i) {
            int row = m0 + w * 32 + mi * 16 + quad * 4 + i;
            #pragma unroll
            for (int ni = 0; ni < NW; ++ni) {
                int col = n0 + ni * 16 + r;
                size_t idx = (size_t)row * N + col;
                float v = acc[mi][ni][i];
                if (EPI == 1) { v += bias[col]; v = (v > 20.f) ? v : log1pf(expf(v)); }
                if (EPI == 2) {
                    v += bias[col];
                    float e = __expf(fminf(1.5957691216f * v + 0.0713548162f * v * v * v, 80.f));
                    v = v * __fdividef(e, e + 1.f);
                }
                if (EPI == 3) { v += resid[idx]; }
                if (EPI == 4) { v += bias[col] + resid[idx]; }
                if (EPI == 2 || EPI == 5) Cb[idx] = f2bf(v);
                else                      Cfo[idx] = v;
            }
        }
    }
}

// ---------------- split-K reduce: out = P0 + P1 + bias + resid -----------
__global__ __launch_bounds__(256) void reduce2_kernel(
        const float* __restrict__ P0, const float* __restrict__ P1,
        const float* __restrict__ bias, const float* __restrict__ resid,
        float* __restrict__ out) {
    size_t idx = ((size_t)blockIdx.x * 256 + threadIdx.x) * 4;
    float4 a = *(const float4*)(P0 + idx);
    float4 b = *(const float4*)(P1 + idx);
    float4 rr = *(const float4*)(resid + idx);
    int col = (int)(idx & (DIMD - 1));
    float4 bb = *(const float4*)(bias + col);
    float4 o;
    o.x = a.x + b.x + rr.x + bb.x;
    o.y = a.y + b.y + rr.y + bb.y;
    o.z = a.z + b.z + rr.z + bb.z;
    o.w = a.w + b.w + rr.w + bb.w;
    *(float4*)(out + idx) = o;
}

// ---------------- fused out_proj reduce + residual + LN2 -----------------
__global__ __launch_bounds__(256) void reduce_ln_kernel(
        const float* __restrict__ P0, const float* __restrict__ P1,
        const float* __restrict__ resid,
        const float* __restrict__ g, const float* __restrict__ b,
        float* __restrict__ x2, u16* __restrict__ out_bf) {
    __shared__ float sm[4];
    int row = blockIdx.x;
    int t = threadIdx.x;
    size_t base = (size_t)row * DIMD + t * 4;
    float4 a  = *(const float4*)(P0 + base);
    float4 p  = *(const float4*)(P1 + base);
    float4 rr = *(const float4*)(resid + base);
    float4 v;
    v.x = a.x + p.x + rr.x;
    v.y = a.y + p.y + rr.y;
    v.z = a.z + p.z + rr.z;
    v.w = a.w + p.w + rr.w;
    *(float4*)(x2 + base) = v;
    float s = v.x + v.y + v.z + v.w;
    for (int off = 32; off > 0; off >>= 1) s += __shfl_down(s, off, 64);
    if ((t & 63) == 0) sm[t >> 6] = s;
    __syncthreads();
    float mu = (sm[0] + sm[1] + sm[2] + sm[3]) * (1.0f / DIMD);
    float dx = v.x - mu, dy = v.y - mu, dz = v.z - mu, dw = v.w - mu;
    float ss = dx*dx + dy*dy + dz*dz + dw*dw;
    for (int off = 32; off > 0; off >>= 1) ss += __shfl_down(ss, off, 64);
    __syncthreads();
    if ((t & 63) == 0) sm[t >> 6] = ss;
    __syncthreads();
    float var = (sm[0] + sm[1] + sm[2] + sm[3]) * (1.0f / DIMD);
    float rs = rsqrtf(var + 1e-5f);
    float4 gv = ((const float4*)g)[t];
    float4 bv = ((const float4*)b)[t];
    u16* o = out_bf + base;
    o[0] = f2bf(dx * rs * gv.x + bv.x);
    o[1] = f2bf(dy * rs * gv.y + bv.y);
    o[2] = f2bf(dz * rs * gv.z + bv.z);
    o[3] = f2bf(dw * rs * gv.w + bv.w);
}

// ---------------- depthwise conv + SiLU, sliding window (8 l / thread) ---
__global__ __launch_bounds__(256) void conv_silu_kernel(
        const u16* __restrict__ xz,
        const float* __restrict__ wx, const float* __restrict__ bx,
        const float* __restrict__ wz, const float* __restrict__ bz,
        u16* __restrict__ u_bf, u16* __restrict__ ycat) {
    int c  = blockIdx.x * 256 + threadIdx.x;   // 0..1023
    int gy = blockIdx.y;                       // 0..NTOK/8-1
    int b  = gy >> 8;
    int l0 = (gy & 255) * 8;
    const u16* base = xz + ((size_t)(b * SEQ + l0)) * DINNER;
    float wxr[4], wzr[4];
    #pragma unroll
    for (int k = 0; k < 4; ++k) { wxr[k] = wx[c * 4 + k]; wzr[k] = wz[c * 4 + k]; }
    float bxv = bx[c], bzv = bz[c];
    float xm1 = (l0 > 0) ? bf2f(base[c - DINNER]) : 0.f;
    float x0v = bf2f(base[c]);
    float x1v = bf2f(base[c + DINNER]);
    float zm1 = (l0 > 0) ? bf2f(base[HALF + c - DINNER]) : 0.f;
    float z0v = bf2f(base[HALF + c]);
    float z1v = bf2f(base[HALF + c + DINNER]);
    u16* up = u_bf + ((size_t)(b * SEQ + l0)) * HALF + c;
    u16* yp = ycat + ((size_t)(b * SEQ + l0)) * DINNER + HALF + c;
    #pragma unroll
    for (int l = 0; l < 8; ++l) {
        bool in = (l0 + l + 2) < SEQ;
        float x2v = in ? bf2f(base[(size_t)(l + 2) * DINNER + c]) : 0.f;
        float z2v = in ? bf2f(base[(size_t)(l + 2) * DINNER + HALF + c]) : 0.f;
        float ax = bxv + wxr[0]*xm1 + wxr[1]*x0v + wxr[2]*x1v + wxr[3]*x2v;
        float az = bzv + wzr[0]*zm1 + wzr[1]*z0v + wzr[2]*z1v + wzr[3]*z2v;
        float sx = ax * __fdividef(1.f, 1.f + __expf(-ax));
        float sz = az * __fdividef(1.f, 1.f + __expf(-az));
        *up = f2bf(sx); *yp = f2bf(sz);
        up += HALF; yp += DINNER;
        xm1 = x0v; x0v = x1v; x1v = x2v;
        zm1 = z0v; z0v = z1v; z1v = z2v;
    }
}

// ---------------- chunk-parallel selective scan (thread per chain) -------
__global__ __launch_bounds__(256) void scan_p1_kernel(
        const float* __restrict__ delta, const u16* __restrict__ u_bf,
        const float* __restrict__ x_dbl, const float* __restrict__ A_log,
        float* __restrict__ hfin, float* __restrict__ dsum) {
    int t  = blockIdx.x * 256 + threadIdx.x;
    int d  = t & (HALF - 1);
    int ch = (t >> 10) & (NCH - 1);
    int b  = t >> 16;
    float Ac[16], h[16];
    #pragma unroll
    for (int i = 0; i < 4; ++i) {
        float4 a = *(const float4*)&A_log[d * DSTATE + i * 4];
        Ac[4*i+0] = -__expf(a.x); Ac[4*i+1] = -__expf(a.y);
        Ac[4*i+2] = -__expf(a.z); Ac[4*i+3] = -__expf(a.w);
        h[4*i+0] = 0.f; h[4*i+1] = 0.f; h[4*i+2] = 0.f; h[4*i+3] = 0.f;
    }
    int l0 = b * SEQ + ch * CL;
    size_t off = (size_t)l0 * HALF + d;
    const float* xrow = x_dbl + (size_t)l0 * 96;
    float ds = 0.f;
    #pragma unroll 4
    for (int l = 0; l < CL; ++l) {
        float dl = delta[off];
        float uv = bf2f(u_bf[off]);
        off += HALF;
        float4 B0 = *(const float4*)(xrow + 64);
        float4 B1 = *(const float4*)(xrow + 68);
        float4 B2 = *(const float4*)(xrow + 72);
        float4 B3 = *(const float4*)(xrow + 76);
        xrow += 96;
        float dBu = dl * uv;
        ds += dl;
        float Bv[16] = {B0.x,B0.y,B0.z,B0.w, B1.x,B1.y,B1.z,B1.w,
                        B2.x,B2.y,B2.z,B2.w, B3.x,B3.y,B3.z,B3.w};
        #pragma unroll
        for (int n = 0; n < 16; ++n)
            h[n] = __expf(dl * Ac[n]) * h[n] + dBu * Bv[n];
    }
    float4* hf = (float4*)&hfin[(size_t)t * 16];
    #pragma unroll
    for (int i = 0; i < 4; ++i)
        hf[i] = (float4){h[4*i+0], h[4*i+1], h[4*i+2], h[4*i+3]};
    dsum[t] = ds;
}

__global__ __launch_bounds__(256) void scan_p2_kernel(
        const float* __restrict__ A_log, const float* __restrict__ dsum,
        const float* __restrict__ hfin, float* __restrict__ hin) {
    int t = blockIdx.x * 256 + threadIdx.x;
    int n = t & 15;
    int d = (t >> 4) & (HALF - 1);
    int b = t >> 14;
    float Ac = -__expf(A_log[d * DSTATE + n]);
    float h = 0.f;
    for (int ch = 0; ch < NCH; ++ch) {
        size_t chain = ((size_t)(b * NCH + ch) * HALF) + d;
        hin[chain * 16 + n] = h;
        float ds = dsum[chain];
        h = __expf(Ac * ds) * h + hfin[chain * 16 + n];
    }
}

__global__ __launch_bounds__(256) void scan_p3_kernel(
        const float* __restrict__ delta, const u16* __restrict__ u_bf,
        const float* __restrict__ x_dbl, const float* __restrict__ A_log,
        const float* __restrict__ Dp, const float* __restrict__ hin,
        u16* __restrict__ ycat) {
    int t  = blockIdx.x * 256 + threadIdx.x;
    int d  = t & (HALF - 1);
    int ch = (t >> 10) & (NCH - 1);
    int b  = t >> 16;
    float Ac[16], h[16];
    #pragma unroll
    for (int i = 0; i < 4; ++i) {
        float4 a  = *(const float4*)&A_log[d * DSTATE + i * 4];
        float4 hv = *(const float4*)&hin[(size_t)t * 16 + i * 4];
        Ac[4*i+0] = -__expf(a.x); Ac[4*i+1] = -__expf(a.y);
        Ac[4*i+2] = -__expf(a.z); Ac[4*i+3] = -__expf(a.w);
        h[4*i+0] = hv.x; h[4*i+1] = hv.y; h[4*i+2] = hv.z; h[4*i+3] = hv.w;
    }
    float Dv = Dp[d];
    int l0 = b * SEQ + ch * CL;
    size_t off = (size_t)l0 * HALF + d;
    const float* xrow = x_dbl + (size_t)l0 * 96;
    u16* yp = ycat + (size_t)l0 * DINNER + d;
    #pragma unroll 4
    for (int l = 0; l < CL; ++l) {
        float dl = delta[off];
        float uv = bf2f(u_bf[off]);
        off += HALF;
        float4 B0 = *(const float4*)(xrow + 64);
        float4 B1 = *(const float4*)(xrow + 68);
        float4 B2 = *(const float4*)(xrow + 72);
        float4 B3 = *(const float4*)(xrow + 76);
        float4 C0 = *(const float4*)(xrow + 80);
        float4 C1 = *(const float4*)(xrow + 84);
        float4 C2 = *(const float4*)(xrow + 88);
        float4 C3 = *(const float4*)(xrow + 92);
        xrow += 96;
        float dBu = dl * uv;
        float Bv[16] = {B0.x,B0.y,B0.z,B0.w, B1.x,B1.y,B1.z,B1.w,
                        B2.x,B2.y,B2.z,B2.w, B3.x,B3.y,B3.z,B3.w};
        float Cv[16] = {C0.x,C0.y,C0.z,C0.w, C1.x,C1.y,C1.z,C1.w,
                        C2.x,C2.y,C2.z,C2.w, C3.x,C3.y,C3.z,C3.w};
        float y = uv * Dv;
        #pragma unroll
        for (int n = 0; n < 16; ++n) {
            h[n] = __expf(dl * Ac[n]) * h[n] + dBu * Bv[n];
            y += h[n] * Cv[n];
        }
        *yp = f2bf(y);
        yp += DINNER;
    }
}

// ---------------- host-side orchestration ----------------
extern "C" void kernel_launch(void* const* d_in, const int* in_sizes, int n_in,
                              void* d_out, int out_size, void* d_ws, size_t ws_size,
                              hipStream_t stream) {
    const float* x         = (const float*)d_in[0];
    const float* ln1_g     = (const float*)d_in[1];
    const float* ln1_b     = (const float*)d_in[2];
    const float* in_proj_w = (const float*)d_in[3];
    const float* conv_x_w  = (const float*)d_in[4];
    const float* conv_x_b  = (const float*)d_in[5];
    const float* conv_z_w  = (const float*)d_in[6];
    const float* conv_z_b  = (const float*)d_in[7];
    const float* x_proj_w  = (const float*)d_in[8];
    const float* dt_proj_w = (const float*)d_in[9];
    const float* dt_proj_b = (const float*)d_in[10];
    const float* A_log     = (const float*)d_in[11];
    const float* Dp        = (const float*)d_in[12];
    const float* out_proj_w= (const float*)d_in[13];
    const float* ln2_g     = (const float*)d_in[14];
    const float* ln2_b     = (const float*)d_in[15];
    const float* mlp_w1    = (const float*)d_in[16];
    const float* mlp_b1    = (const float*)d_in[17];
    const float* mlp_w2    = (const float*)d_in[18];
    const float* mlp_b2    = (const float*)d_in[19];
    float* out = (float*)d_out;

    char* p = (char*)d_ws;
    auto alloc = [&](size_t bytes) {
        char* r = p; p += (bytes + 255) & ~(size_t)255; return r;
    };
    u16*   w_in   = (u16*)  alloc((size_t)DINNER * DIMD * 2);
    u16*   w_xp   = (u16*)  alloc((size_t)96 * HALF * 2);
    u16*   w_dt   = (u16*)  alloc((size_t)HALF * DTRANK * 2);
    u16*   w_out  = (u16*)  alloc((size_t)DIMD * DINNER * 2);
    u16*   w_m1   = (u16*)  alloc((size_t)MLPD * DIMD * 2);
    u16*   w_m2   = (u16*)  alloc((size_t)DIMD * MLPD * 2);
    u16*   xn_bf  = (u16*)  alloc((size_t)NTOK * DIMD * 2);
    u16*   xz_bf  = (u16*)  alloc((size_t)NTOK * DINNER * 2);  // 16 MB
    u16*   u_bf   = (u16*)  alloc((size_t)NTOK * HALF * 2);
    u16*   ycat   = (u16*)  alloc((size_t)NTOK * DINNER * 2);
    float* x_dbl  = (float*)alloc((size_t)NTOK * 96 * 4);
    u16*   xdbl_bf= (u16*)  alloc((size_t)NTOK * 96 * 2);
    float* delta  = (float*)alloc((size_t)NTOK * HALF * 4);    // 16 MB
    float* x2     = (float*)alloc((size_t)NTOK * DIMD * 4);
    u16*   ln2_bf = (u16*)  alloc((size_t)NTOK * DIMD * 2);
    u16*   mlp_h  = (u16*)  alloc((size_t)NTOK * MLPD * 2);    // 32 MB
    // scan scratch aliases mlp_h (dead until mlp1):
    float* hfin = (float*)mlp_h;
    float* hin  = hfin + (size_t)BSZ * NCH * HALF * DSTATE;
    float* dsum = hin  + (size_t)BSZ * NCH * HALF * DSTATE;
    // split-K partials alias delta (dead after scan) and xz_bf (dead after conv):
    float* P0 = delta;
    float* P1 = (float*)xz_bf;

    // fused LN1 + weight conversions
    cvtln_kernel<<<NTOK + CVT_BLOCKS, 256, 0, stream>>>(
        x, ln1_g, ln1_b, xn_bf,
        in_proj_w, w_in, x_proj_w, w_xp, dt_proj_w, w_dt,
        out_proj_w, w_out, mlp_w1, w_m1, mlp_w2, w_m2);

    // in_proj: xz_bf[4096,2048] = xn @ W^T (bf16 out)
    gemm128_kernel<5,64,1><<<dim3(NTOK/128, DINNER/64), 256, 0, stream>>>(
        xn_bf, DIMD, w_in, DIMD, DINNER, nullptr, nullptr, nullptr, nullptr, xz_bf);

    // depthwise conv + silu (sliding window)
    conv_silu_kernel<<<dim3(HALF/256, NTOK/8), 256, 0, stream>>>(
        xz_bf, conv_x_w, conv_x_b, conv_z_w, conv_z_b, u_bf, ycat);

    // x_proj: [4096,96] = u @ W^T  (split-K in block)
    gemm_small_kernel<<<dim3(NTOK/32, 96/16), 256, 0, stream>>>(
        u_bf, HALF, w_xp, HALF, 96, x_dbl, xdbl_bf);

    // dt_proj: delta = softplus(dt @ W^T + b)
    gemm128_kernel<1,64,1><<<dim3(NTOK/128, HALF/64), 256, 0, stream>>>(
        xdbl_bf, 96, w_dt, DTRANK, HALF, dt_proj_b, nullptr, delta, nullptr, nullptr);

    // chunk-parallel scan
    scan_p1_kernel<<<(BSZ*NCH*HALF)/256, 256, 0, stream>>>(
        delta, u_bf, x_dbl, A_log, hfin, dsum);
    scan_p2_kernel<<<(BSZ*HALF*DSTATE)/256, 256, 0, stream>>>(
        A_log, dsum, hfin, hin);
    scan_p3_kernel<<<(BSZ*NCH*HALF)/256, 256, 0, stream>>>(
        delta, u_bf, x_dbl, A_log, Dp, hin, ycat);

    // out_proj split-K=2: P = ycat @ W^T
    gemm128_kernel<0,64,2><<<dim3(NTOK/128, DIMD/64, 2), 256, 0, stream>>>(
        ycat, DINNER, w_out, DINNER, DIMD, nullptr, nullptr, P0, P1, nullptr);
    // fused: x2 = P0+P1+x ; ln2_bf = LN(x2)
    reduce_ln_kernel<<<NTOK, 256, 0, stream>>>(
        P0, P1, x, ln2_g, ln2_b, x2, ln2_bf);

    // MLP1: gelu(ln2 @ W1^T + b1) -> bf16 (overwrites scan scratch - ok)
    gemm128_kernel<2,64,1><<<dim3(NTOK/128, MLPD/64), 256, 0, stream>>>(
        ln2_bf, DIMD, w_m1, DIMD, MLPD, mlp_b1, nullptr, nullptr, nullptr, mlp_h);

    // MLP2 split-K=2: P = mlp_h @ W2^T ; out = P0+P1+b2+x2
    gemm128_kernel<0,64,2><<<dim3(NTOK/128, DIMD/64, 2), 256, 0, stream>>>(
        mlp_h, MLPD, w_m2, MLPD, DIMD, nullptr, nullptr, P0, P1, nullptr);
    reduce2_kernel<<<(NTOK*DIMD)/1024, 256, 0, stream>>>(
        P0, P1, mlp_b2, x2, out);
}

// Round 9
// 453.123 us; speedup vs baseline: 1.1402x; 1.1402x over previous
//
#include <hip/hip_runtime.h>
#include <math.h>

#define DIMD    1024
#define MLPD    4096
#define DSTATE  16
#define DCONV   4
#define HALF    1024
#define DINNER  2048
#define DTRANK  64
#define BSZ     2
#define SEQ     2048
#define NTOK    (BSZ*SEQ)   // 4096
#define NCH     64
#define CL      (SEQ/NCH)   // 32

typedef short bf16x8 __attribute__((ext_vector_type(8)));
typedef float f32x4  __attribute__((ext_vector_type(4)));
typedef unsigned short u16;
typedef unsigned int   u32;

__device__ __forceinline__ u16 f2bf(float x) {
    union { float f; unsigned int u; } v; v.f = x;
    unsigned int r = (v.u + 0x7FFFu + ((v.u >> 16) & 1u)) >> 16;
    return (u16)r;
}
__device__ __forceinline__ float bf2f(u16 x) {
    union { unsigned int u; float f; } v; v.u = ((unsigned int)x) << 16;
    return v.f;
}

// ---------------- fused LN1 + weight f32->bf16 convert -------------------
#define SZ_WIN  (DINNER*DIMD)
#define SZ_WXP  (96*HALF)
#define SZ_WDT  (HALF*DTRANK)
#define SZ_WOUT (DIMD*DINNER)
#define SZ_WM1  (MLPD*DIMD)
#define SZ_WM2  (DIMD*MLPD)
#define SZ_TOT  (SZ_WIN+SZ_WXP+SZ_WDT+SZ_WOUT+SZ_WM1+SZ_WM2)
#define CVT_BLOCKS ((SZ_TOT + 255) / 256)

__global__ __launch_bounds__(256) void cvtln_kernel(
        const float* __restrict__ x, const float* __restrict__ g,
        const float* __restrict__ b, u16* __restrict__ xn_bf,
        const float* __restrict__ s0, u16* __restrict__ d0,
        const float* __restrict__ s1, u16* __restrict__ d1,
        const float* __restrict__ s2, u16* __restrict__ d2,
        const float* __restrict__ s3, u16* __restrict__ d3,
        const float* __restrict__ s4, u16* __restrict__ d4,
        const float* __restrict__ s5, u16* __restrict__ d5) {
    if (blockIdx.x >= NTOK) {
        int i = (blockIdx.x - NTOK) * 256 + threadIdx.x;
        if (i < SZ_WIN)  { d0[i] = f2bf(s0[i]); return; }  i -= SZ_WIN;
        if (i < SZ_WXP)  { d1[i] = f2bf(s1[i]); return; }  i -= SZ_WXP;
        if (i < SZ_WDT)  { d2[i] = f2bf(s2[i]); return; }  i -= SZ_WDT;
        if (i < SZ_WOUT) { d3[i] = f2bf(s3[i]); return; }  i -= SZ_WOUT;
        if (i < SZ_WM1)  { d4[i] = f2bf(s4[i]); return; }  i -= SZ_WM1;
        if (i < SZ_WM2)  { d5[i] = f2bf(s5[i]); }
        return;
    }
    __shared__ float sm[4];
    int row = blockIdx.x;
    int t = threadIdx.x;
    const float4* xr = (const float4*)(x + (size_t)row * DIMD);
    float4 v = xr[t];
    float s = v.x + v.y + v.z + v.w;
    for (int off = 32; off > 0; off >>= 1) s += __shfl_down(s, off, 64);
    if ((t & 63) == 0) sm[t >> 6] = s;
    __syncthreads();
    float mu = (sm[0] + sm[1] + sm[2] + sm[3]) * (1.0f / DIMD);
    float dx = v.x - mu, dy = v.y - mu, dz = v.z - mu, dw = v.w - mu;
    float ss = dx*dx + dy*dy + dz*dz + dw*dw;
    for (int off = 32; off > 0; off >>= 1) ss += __shfl_down(ss, off, 64);
    __syncthreads();
    if ((t & 63) == 0) sm[t >> 6] = ss;
    __syncthreads();
    float var = (sm[0] + sm[1] + sm[2] + sm[3]) * (1.0f / DIMD);
    float rs = rsqrtf(var + 1e-5f);
    float4 gv = ((const float4*)g)[t];
    float4 bv = ((const float4*)b)[t];
    u16* o = xn_bf + (size_t)row * DIMD + t * 4;
    o[0] = f2bf(dx * rs * gv.x + bv.x);
    o[1] = f2bf(dy * rs * gv.y + bv.y);
    o[2] = f2bf(dz * rs * gv.z + bv.z);
    o[3] = f2bf(dw * rs * gv.w + bv.w);
}

// ---------------- x_proj GEMM: 4 waves = 2 m-tiles x 2 K-halves ----------
__global__ __launch_bounds__(256) void gemm_small_kernel(
        const u16* __restrict__ A, int lda,
        const u16* __restrict__ W, int K, int N,
        float* __restrict__ Cf, u16* __restrict__ Cb) {
    __shared__ f32x4 red[2][64];
    int t = threadIdx.x;
    int w = t >> 6, lane = t & 63;
    int mt = w & 1, kh = w >> 1;
    int m0 = blockIdx.x * 32 + mt * 16;
    int n0 = blockIdx.y * 16;
    int r = lane & 15, quad = lane >> 4;
    int Kh = K >> 1;
    f32x4 acc = {0.f, 0.f, 0.f, 0.f};
    const u16* ap = A + (size_t)(m0 + r) * lda + kh * Kh + quad * 8;
    const u16* wp = W + (size_t)(n0 + r) * K   + kh * Kh + quad * 8;
    for (int k = 0; k < Kh; k += 32) {
        bf16x8 av = *(const bf16x8*)(ap + k);
        bf16x8 bv = *(const bf16x8*)(wp + k);
        acc = __builtin_amdgcn_mfma_f32_16x16x32_bf16(av, bv, acc, 0, 0, 0);
    }
    if (kh == 1) red[mt][lane] = acc;
    __syncthreads();
    if (kh == 0) {
        f32x4 o = red[mt][lane];
        int col = n0 + r;
        #pragma unroll
        for (int i = 0; i < 4; ++i) {
            int row = m0 + quad * 4 + i;
            size_t idx = (size_t)row * N + col;
            float v = acc[i] + o[i];
            Cf[idx] = v;
            Cb[idx] = f2bf(v);
        }
    }
}

// ---------------- dt_proj GEMM: K=64, bias+softplus (2 MFMAs/wave) -------
// 4 waves = 2m x 2n 16x16 tiles. grid (M/32, N/32).
__global__ __launch_bounds__(256) void gemm_k64_kernel(
        const u16* __restrict__ A, int lda,
        const u16* __restrict__ W, int N,
        const float* __restrict__ bias, float* __restrict__ Cf) {
    int t = threadIdx.x;
    int w = t >> 6, lane = t & 63;
    int mt = w & 1, nt = w >> 1;
    int m0 = blockIdx.x * 32 + mt * 16;
    int n0 = blockIdx.y * 32 + nt * 16;
    int r = lane & 15, quad = lane >> 4;
    const u16* ap = A + (size_t)(m0 + r) * lda + quad * 8;
    const u16* wp = W + (size_t)(n0 + r) * DTRANK + quad * 8;
    bf16x8 a0 = *(const bf16x8*)ap;
    bf16x8 a1 = *(const bf16x8*)(ap + 32);
    bf16x8 b0 = *(const bf16x8*)wp;
    bf16x8 b1 = *(const bf16x8*)(wp + 32);
    f32x4 acc = {0.f, 0.f, 0.f, 0.f};
    acc = __builtin_amdgcn_mfma_f32_16x16x32_bf16(a0, b0, acc, 0, 0, 0);
    acc = __builtin_amdgcn_mfma_f32_16x16x32_bf16(a1, b1, acc, 0, 0, 0);
    int col = n0 + r;
    float bv = bias[col];
    #pragma unroll
    for (int i = 0; i < 4; ++i) {
        int row = m0 + quad * 4 + i;
        float v = acc[i] + bv;
        v = (v > 20.f) ? v : log1pf(expf(v));
        Cf[(size_t)row * N + col] = v;
    }
}

// ---------------- big GEMM: 128xTN tile, BK=32, dbuf, hoisted addrs ------
// (R7 structure: A+B both via global_load_lds, XOR swizzle, 1 barrier/phase)
// EPI: 0 f32 | 2 bias+gelu(tanh) bf16 | 5 plain bf16
// KS: K-split count; blockIdx.z selects slice; partial -> C0..C3 by z.
template<int EPI, int TN, int KS>
__global__ __launch_bounds__(256) void gemm128_kernel(
        const u16* __restrict__ A, int lda, const u16* __restrict__ W,
        int K, int N,
        const float* __restrict__ bias,
        float* __restrict__ C0, float* __restrict__ C1,
        float* __restrict__ C2, float* __restrict__ C3,
        u16* __restrict__ Cb) {
    constexpr int NF = TN / 32;
    __shared__ u16 As0[128 * 32], As1[128 * 32];
    __shared__ u16 Bs0[TN * 32],  Bs1[TN * 32];
    const int t = threadIdx.x;
    const int w = t >> 6;
    const int lane = t & 63;
    const int r = lane & 15, quad = lane >> 4;
    const int wm = w & 1, wn = w >> 1;
    const int m0 = blockIdx.x * 128;
    const int n0 = blockIdx.y * TN;
    const int Kloc = K / KS;
    const int kz = (KS > 1) ? blockIdx.z : 0;

    f32x4 acc[4][NF];
    #pragma unroll
    for (int mi = 0; mi < 4; ++mi)
        #pragma unroll
        for (int ni = 0; ni < NF; ++ni)
            acc[mi][ni] = (f32x4){0.f, 0.f, 0.f, 0.f};

    const u16* pa[2];
    const u16* pb[NF / 2];
    #pragma unroll
    for (int i = 0; i < 2; ++i) {
        int c = (i * 4 + w) * 64 + lane;
        int row = c >> 2;
        int q = (c & 3) ^ ((row >> 1) & 3);
        pa[i] = A + (size_t)(m0 + row) * lda + (size_t)kz * Kloc + q * 8;
    }
    #pragma unroll
    for (int i = 0; i < NF / 2; ++i) {
        int c = (i * 4 + w) * 64 + lane;
        int row = c >> 2;
        int q = (c & 3) ^ ((row >> 1) & 3);
        pb[i] = W + (size_t)(n0 + row) * K + (size_t)kz * Kloc + q * 8;
    }
    const int qs = quad ^ ((r >> 1) & 3);
    int aoff[4], boff[NF];
    #pragma unroll
    for (int mi = 0; mi < 4; ++mi)
        aoff[mi] = (wm * 64 + mi * 16 + r) * 32 + qs * 8;
    #pragma unroll
    for (int ni = 0; ni < NF; ++ni)
        boff[ni] = (wn * (TN / 2) + ni * 16 + r) * 32 + qs * 8;

    auto stage = [&](u16* __restrict__ Ad, u16* __restrict__ Bd) {
        #pragma unroll
        for (int i = 0; i < 2; ++i) {
            __builtin_amdgcn_global_load_lds(
                (const __attribute__((address_space(1))) u32*)pa[i],
                (__attribute__((address_space(3))) u32*)(Ad + (i * 4 + w) * 512),
                16, 0, 0);
            pa[i] += 32;
        }
        #pragma unroll
        for (int i = 0; i < NF / 2; ++i) {
            __builtin_amdgcn_global_load_lds(
                (const __attribute__((address_space(1))) u32*)pb[i],
                (__attribute__((address_space(3))) u32*)(Bd + (i * 4 + w) * 512),
                16, 0, 0);
            pb[i] += 32;
        }
    };
    auto compute = [&](const u16* __restrict__ Ab, const u16* __restrict__ Bb) {
        bf16x8 af[4], bfr[NF];
        #pragma unroll
        for (int mi = 0; mi < 4; ++mi) af[mi] = *(const bf16x8*)(Ab + aoff[mi]);
        #pragma unroll
        for (int ni = 0; ni < NF; ++ni) bfr[ni] = *(const bf16x8*)(Bb + boff[ni]);
        #pragma unroll
        for (int mi = 0; mi < 4; ++mi)
            #pragma unroll
            for (int ni = 0; ni < NF; ++ni)
                acc[mi][ni] = __builtin_amdgcn_mfma_f32_16x16x32_bf16(
                    af[mi], bfr[ni], acc[mi][ni], 0, 0, 0);
    };

    stage(As0, Bs0);
    for (int k0 = 0; k0 < Kloc; k0 += 64) {
        __syncthreads();
        if (k0 + 32 < Kloc) stage(As1, Bs1);
        compute(As0, Bs0);
        __syncthreads();
        if (k0 + 64 < Kloc) stage(As0, Bs0);
        compute(As1, Bs1);
    }

    float* Cfo = (kz == 0) ? C0 : (kz == 1) ? C1 : (kz == 2) ? C2 : C3;
    #pragma unroll
    for (int mi = 0; mi < 4; ++mi) {
        #pragma unroll
        for (int i = 0; i < 4; ++i) {
            int row = m0 + wm * 64 + mi * 16 + quad * 4 + i;
            #pragma unroll
            for (int ni = 0; ni < NF; ++ni) {
                int col = n0 + wn * (TN / 2) + ni * 16 + r;
                size_t idx = (size_t)row * N + col;
                float v = acc[mi][ni][i];
                if (EPI == 2) {
                    v += bias[col];
                    float e = __expf(fminf(1.5957691216f * v + 0.0713548162f * v * v * v, 80.f));
                    v = v * __fdividef(e, e + 1.f);
                }
                if (EPI == 2 || EPI == 5) Cb[idx] = f2bf(v);
                else                      Cfo[idx] = v;
            }
        }
    }
}

// ---------------- split-K=4 reduce: out = sum(P) + bias + resid ----------
__global__ __launch_bounds__(256) void reduce4_kernel(
        const float* __restrict__ P0, const float* __restrict__ P1,
        const float* __restrict__ P2, const float* __restrict__ P3,
        const float* __restrict__ bias, const float* __restrict__ resid,
        float* __restrict__ out) {
    size_t idx = ((size_t)blockIdx.x * 256 + threadIdx.x) * 4;
    float4 a = *(const float4*)(P0 + idx);
    float4 b = *(const float4*)(P1 + idx);
    float4 c = *(const float4*)(P2 + idx);
    float4 d = *(const float4*)(P3 + idx);
    float4 rr = *(const float4*)(resid + idx);
    int col = (int)(idx & (DIMD - 1));
    float4 bb = *(const float4*)(bias + col);
    float4 o;
    o.x = a.x + b.x + c.x + d.x + rr.x + bb.x;
    o.y = a.y + b.y + c.y + d.y + rr.y + bb.y;
    o.z = a.z + b.z + c.z + d.z + rr.z + bb.z;
    o.w = a.w + b.w + c.w + d.w + rr.w + bb.w;
    *(float4*)(out + idx) = o;
}

// ---------------- fused out_proj reduce(4) + residual + LN2 --------------
__global__ __launch_bounds__(256) void reduce_ln4_kernel(
        const float* __restrict__ P0, const float* __restrict__ P1,
        const float* __restrict__ P2, const float* __restrict__ P3,
        const float* __restrict__ resid,
        const float* __restrict__ g, const float* __restrict__ b,
        float* __restrict__ x2, u16* __restrict__ out_bf) {
    __shared__ float sm[4];
    int row = blockIdx.x;
    int t = threadIdx.x;
    size_t base = (size_t)row * DIMD + t * 4;
    float4 a  = *(const float4*)(P0 + base);
    float4 p  = *(const float4*)(P1 + base);
    float4 c  = *(const float4*)(P2 + base);
    float4 d  = *(const float4*)(P3 + base);
    float4 rr = *(const float4*)(resid + base);
    float4 v;
    v.x = a.x + p.x + c.x + d.x + rr.x;
    v.y = a.y + p.y + c.y + d.y + rr.y;
    v.z = a.z + p.z + c.z + d.z + rr.z;
    v.w = a.w + p.w + c.w + d.w + rr.w;
    *(float4*)(x2 + base) = v;
    float s = v.x + v.y + v.z + v.w;
    for (int off = 32; off > 0; off >>= 1) s += __shfl_down(s, off, 64);
    if ((t & 63) == 0) sm[t >> 6] = s;
    __syncthreads();
    float mu = (sm[0] + sm[1] + sm[2] + sm[3]) * (1.0f / DIMD);
    float dx = v.x - mu, dy = v.y - mu, dz = v.z - mu, dw = v.w - mu;
    float ss = dx*dx + dy*dy + dz*dz + dw*dw;
    for (int off = 32; off > 0; off >>= 1) ss += __shfl_down(ss, off, 64);
    __syncthreads();
    if ((t & 63) == 0) sm[t >> 6] = ss;
    __syncthreads();
    float var = (sm[0] + sm[1] + sm[2] + sm[3]) * (1.0f / DIMD);
    float rs = rsqrtf(var + 1e-5f);
    float4 gv = ((const float4*)g)[t];
    float4 bv = ((const float4*)b)[t];
    u16* o = out_bf + base;
    o[0] = f2bf(dx * rs * gv.x + bv.x);
    o[1] = f2bf(dy * rs * gv.y + bv.y);
    o[2] = f2bf(dz * rs * gv.z + bv.z);
    o[3] = f2bf(dw * rs * gv.w + bv.w);
}

// ---------------- depthwise conv + SiLU, sliding window (8 l / thread) ---
__global__ __launch_bounds__(256) void conv_silu_kernel(
        const u16* __restrict__ xz,
        const float* __restrict__ wx, const float* __restrict__ bx,
        const float* __restrict__ wz, const float* __restrict__ bz,
        u16* __restrict__ u_bf, u16* __restrict__ ycat) {
    int c  = blockIdx.x * 256 + threadIdx.x;   // 0..1023
    int gy = blockIdx.y;                       // 0..NTOK/8-1
    int b  = gy >> 8;
    int l0 = (gy & 255) * 8;
    const u16* base = xz + ((size_t)(b * SEQ + l0)) * DINNER;
    float wxr[4], wzr[4];
    #pragma unroll
    for (int k = 0; k < 4; ++k) { wxr[k] = wx[c * 4 + k]; wzr[k] = wz[c * 4 + k]; }
    float bxv = bx[c], bzv = bz[c];
    float xm1 = (l0 > 0) ? bf2f(base[c - DINNER]) : 0.f;
    float x0v = bf2f(base[c]);
    float x1v = bf2f(base[c + DINNER]);
    float zm1 = (l0 > 0) ? bf2f(base[HALF + c - DINNER]) : 0.f;
    float z0v = bf2f(base[HALF + c]);
    float z1v = bf2f(base[HALF + c + DINNER]);
    u16* up = u_bf + ((size_t)(b * SEQ + l0)) * HALF + c;
    u16* yp = ycat + ((size_t)(b * SEQ + l0)) * DINNER + HALF + c;
    #pragma unroll
    for (int l = 0; l < 8; ++l) {
        bool in = (l0 + l + 2) < SEQ;
        float x2v = in ? bf2f(base[(size_t)(l + 2) * DINNER + c]) : 0.f;
        float z2v = in ? bf2f(base[(size_t)(l + 2) * DINNER + HALF + c]) : 0.f;
        float ax = bxv + wxr[0]*xm1 + wxr[1]*x0v + wxr[2]*x1v + wxr[3]*x2v;
        float az = bzv + wzr[0]*zm1 + wzr[1]*z0v + wzr[2]*z1v + wzr[3]*z2v;
        float sx = ax * __fdividef(1.f, 1.f + __expf(-ax));
        float sz = az * __fdividef(1.f, 1.f + __expf(-az));
        *up = f2bf(sx); *yp = f2bf(sz);
        up += HALF; yp += DINNER;
        xm1 = x0v; x0v = x1v; x1v = x2v;
        zm1 = z0v; z0v = z1v; z1v = z2v;
    }
}

// ---------------- chunk-parallel selective scan (thread per chain) -------
__global__ __launch_bounds__(256) void scan_p1_kernel(
        const float* __restrict__ delta, const u16* __restrict__ u_bf,
        const float* __restrict__ x_dbl, const float* __restrict__ A_log,
        float* __restrict__ hfin, float* __restrict__ dsum) {
    int t  = blockIdx.x * 256 + threadIdx.x;
    int d  = t & (HALF - 1);
    int ch = (t >> 10) & (NCH - 1);
    int b  = t >> 16;
    float Ac[16], h[16];
    #pragma unroll
    for (int i = 0; i < 4; ++i) {
        float4 a = *(const float4*)&A_log[d * DSTATE + i * 4];
        Ac[4*i+0] = -__expf(a.x); Ac[4*i+1] = -__expf(a.y);
        Ac[4*i+2] = -__expf(a.z); Ac[4*i+3] = -__expf(a.w);
        h[4*i+0] = 0.f; h[4*i+1] = 0.f; h[4*i+2] = 0.f; h[4*i+3] = 0.f;
    }
    int l0 = b * SEQ + ch * CL;
    size_t off = (size_t)l0 * HALF + d;
    const float* xrow = x_dbl + (size_t)l0 * 96;
    float ds = 0.f;
    #pragma unroll 4
    for (int l = 0; l < CL; ++l) {
        float dl = delta[off];
        float uv = bf2f(u_bf[off]);
        off += HALF;
        float4 B0 = *(const float4*)(xrow + 64);
        float4 B1 = *(const float4*)(xrow + 68);
        float4 B2 = *(const float4*)(xrow + 72);
        float4 B3 = *(const float4*)(xrow + 76);
        xrow += 96;
        float dBu = dl * uv;
        ds += dl;
        float Bv[16] = {B0.x,B0.y,B0.z,B0.w, B1.x,B1.y,B1.z,B1.w,
                        B2.x,B2.y,B2.z,B2.w, B3.x,B3.y,B3.z,B3.w};
        #pragma unroll
        for (int n = 0; n < 16; ++n)
            h[n] = __expf(dl * Ac[n]) * h[n] + dBu * Bv[n];
    }
    float4* hf = (float4*)&hfin[(size_t)t * 16];
    #pragma unroll
    for (int i = 0; i < 4; ++i)
        hf[i] = (float4){h[4*i+0], h[4*i+1], h[4*i+2], h[4*i+3]};
    dsum[t] = ds;
}

__global__ __launch_bounds__(256) void scan_p2_kernel(
        const float* __restrict__ A_log, const float* __restrict__ dsum,
        const float* __restrict__ hfin, float* __restrict__ hin) {
    int t = blockIdx.x * 256 + threadIdx.x;
    int n = t & 15;
    int d = (t >> 4) & (HALF - 1);
    int b = t >> 14;
    float Ac = -__expf(A_log[d * DSTATE + n]);
    float h = 0.f;
    for (int ch = 0; ch < NCH; ++ch) {
        size_t chain = ((size_t)(b * NCH + ch) * HALF) + d;
        hin[chain * 16 + n] = h;
        float ds = dsum[chain];
        h = __expf(Ac * ds) * h + hfin[chain * 16 + n];
    }
}

__global__ __launch_bounds__(256) void scan_p3_kernel(
        const float* __restrict__ delta, const u16* __restrict__ u_bf,
        const float* __restrict__ x_dbl, const float* __restrict__ A_log,
        const float* __restrict__ Dp, const float* __restrict__ hin,
        u16* __restrict__ ycat) {
    int t  = blockIdx.x * 256 + threadIdx.x;
    int d  = t & (HALF - 1);
    int ch = (t >> 10) & (NCH - 1);
    int b  = t >> 16;
    float Ac[16], h[16];
    #pragma unroll
    for (int i = 0; i < 4; ++i) {
        float4 a  = *(const float4*)&A_log[d * DSTATE + i * 4];
        float4 hv = *(const float4*)&hin[(size_t)t * 16 + i * 4];
        Ac[4*i+0] = -__expf(a.x); Ac[4*i+1] = -__expf(a.y);
        Ac[4*i+2] = -__expf(a.z); Ac[4*i+3] = -__expf(a.w);
        h[4*i+0] = hv.x; h[4*i+1] = hv.y; h[4*i+2] = hv.z; h[4*i+3] = hv.w;
    }
    float Dv = Dp[d];
    int l0 = b * SEQ + ch * CL;
    size_t off = (size_t)l0 * HALF + d;
    const float* xrow = x_dbl + (size_t)l0 * 96;
    u16* yp = ycat + (size_t)l0 * DINNER + d;
    #pragma unroll 4
    for (int l = 0; l < CL; ++l) {
        float dl = delta[off];
        float uv = bf2f(u_bf[off]);
        off += HALF;
        float4 B0 = *(const float4*)(xrow + 64);
        float4 B1 = *(const float4*)(xrow + 68);
        float4 B2 = *(const float4*)(xrow + 72);
        float4 B3 = *(const float4*)(xrow + 76);
        float4 C0 = *(const float4*)(xrow + 80);
        float4 C1 = *(const float4*)(xrow + 84);
        float4 C2 = *(const float4*)(xrow + 88);
        float4 C3 = *(const float4*)(xrow + 92);
        xrow += 96;
        float dBu = dl * uv;
        float Bv[16] = {B0.x,B0.y,B0.z,B0.w, B1.x,B1.y,B1.z,B1.w,
                        B2.x,B2.y,B2.z,B2.w, B3.x,B3.y,B3.z,B3.w};
        float Cv[16] = {C0.x,C0.y,C0.z,C0.w, C1.x,C1.y,C1.z,C1.w,
                        C2.x,C2.y,C2.z,C2.w, C3.x,C3.y,C3.z,C3.w};
        float y = uv * Dv;
        #pragma unroll
        for (int n = 0; n < 16; ++n) {
            h[n] = __expf(dl * Ac[n]) * h[n] + dBu * Bv[n];
            y += h[n] * Cv[n];
        }
        *yp = f2bf(y);
        yp += DINNER;
    }
}

// ---------------- host-side orchestration ----------------
extern "C" void kernel_launch(void* const* d_in, const int* in_sizes, int n_in,
                              void* d_out, int out_size, void* d_ws, size_t ws_size,
                              hipStream_t stream) {
    const float* x         = (const float*)d_in[0];
    const float* ln1_g     = (const float*)d_in[1];
    const float* ln1_b     = (const float*)d_in[2];
    const float* in_proj_w = (const float*)d_in[3];
    const float* conv_x_w  = (const float*)d_in[4];
    const float* conv_x_b  = (const float*)d_in[5];
    const float* conv_z_w  = (const float*)d_in[6];
    const float* conv_z_b  = (const float*)d_in[7];
    const float* x_proj_w  = (const float*)d_in[8];
    const float* dt_proj_w = (const float*)d_in[9];
    const float* dt_proj_b = (const float*)d_in[10];
    const float* A_log     = (const float*)d_in[11];
    const float* Dp        = (const float*)d_in[12];
    const float* out_proj_w= (const float*)d_in[13];
    const float* ln2_g     = (const float*)d_in[14];
    const float* ln2_b     = (const float*)d_in[15];
    const float* mlp_w1    = (const float*)d_in[16];
    const float* mlp_b1    = (const float*)d_in[17];
    const float* mlp_w2    = (const float*)d_in[18];
    const float* mlp_b2    = (const float*)d_in[19];
    float* out = (float*)d_out;

    char* p = (char*)d_ws;
    auto alloc = [&](size_t bytes) {
        char* r = p; p += (bytes + 255) & ~(size_t)255; return r;
    };
    u16*   w_in   = (u16*)  alloc((size_t)DINNER * DIMD * 2);
    u16*   w_xp   = (u16*)  alloc((size_t)96 * HALF * 2);
    u16*   w_dt   = (u16*)  alloc((size_t)HALF * DTRANK * 2);
    u16*   w_out  = (u16*)  alloc((size_t)DIMD * DINNER * 2);
    u16*   w_m1   = (u16*)  alloc((size_t)MLPD * DIMD * 2);
    u16*   w_m2   = (u16*)  alloc((size_t)DIMD * MLPD * 2);
    u16*   xn_bf  = (u16*)  alloc((size_t)NTOK * DIMD * 2);
    u16*   xz_bf  = (u16*)  alloc((size_t)NTOK * DINNER * 2);  // 16 MB
    u16*   u_bf   = (u16*)  alloc((size_t)NTOK * HALF * 2);
    u16*   ycat   = (u16*)  alloc((size_t)NTOK * DINNER * 2);  // 16 MB
    float* x_dbl  = (float*)alloc((size_t)NTOK * 96 * 4);
    u16*   xdbl_bf= (u16*)  alloc((size_t)NTOK * 96 * 2);
    float* delta  = (float*)alloc((size_t)NTOK * HALF * 4);    // 16 MB
    float* x2     = (float*)alloc((size_t)NTOK * DIMD * 4);
    u16*   ln2_bf = (u16*)  alloc((size_t)NTOK * DIMD * 2);
    u16*   mlp_h  = (u16*)  alloc((size_t)NTOK * MLPD * 2);    // 32 MB
    float* Px     = (float*)alloc((size_t)NTOK * DIMD * 4);    // 16 MB extra partial
    // scan scratch aliases mlp_h (dead until out_proj):
    float* hfin = (float*)mlp_h;
    float* hin  = hfin + (size_t)BSZ * NCH * HALF * DSTATE;
    float* dsum = hin  + (size_t)BSZ * NCH * HALF * DSTATE;
    // split-K partials:
    float* P0 = delta;              // dead after scan
    float* P1 = (float*)xz_bf;      // dead after conv
    float* P2o = (float*)mlp_h;                          // out_proj: mlp_h lower half
    float* P3o = (float*)mlp_h + (size_t)NTOK * DIMD;    // out_proj: mlp_h upper half
    float* P2m = (float*)ycat;      // mlp2: ycat dead after out_proj
    float* P3m = Px;                // mlp2: dedicated

    // fused LN1 + weight conversions
    cvtln_kernel<<<NTOK + CVT_BLOCKS, 256, 0, stream>>>(
        x, ln1_g, ln1_b, xn_bf,
        in_proj_w, w_in, x_proj_w, w_xp, dt_proj_w, w_dt,
        out_proj_w, w_out, mlp_w1, w_m1, mlp_w2, w_m2);

    // in_proj: xz_bf[4096,2048] = xn @ W^T (bf16 out)
    gemm128_kernel<5,64,1><<<dim3(NTOK/128, DINNER/64), 256, 0, stream>>>(
        xn_bf, DIMD, w_in, DIMD, DINNER, nullptr,
        nullptr, nullptr, nullptr, nullptr, xz_bf);

    // depthwise conv + silu (sliding window)
    conv_silu_kernel<<<dim3(HALF/256, NTOK/8), 256, 0, stream>>>(
        xz_bf, conv_x_w, conv_x_b, conv_z_w, conv_z_b, u_bf, ycat);

    // x_proj: [4096,96] = u @ W^T  (split-K in block)
    gemm_small_kernel<<<dim3(NTOK/32, 96/16), 256, 0, stream>>>(
        u_bf, HALF, w_xp, HALF, 96, x_dbl, xdbl_bf);

    // dt_proj: delta = softplus(dt @ W^T + b)   (K=64 kernel, 4096 blocks)
    gemm_k64_kernel<<<dim3(NTOK/32, HALF/32), 256, 0, stream>>>(
        xdbl_bf, 96, w_dt, HALF, dt_proj_b, delta);

    // chunk-parallel scan
    scan_p1_kernel<<<(BSZ*NCH*HALF)/256, 256, 0, stream>>>(
        delta, u_bf, x_dbl, A_log, hfin, dsum);
    scan_p2_kernel<<<(BSZ*HALF*DSTATE)/256, 256, 0, stream>>>(
        A_log, dsum, hfin, hin);
    scan_p3_kernel<<<(BSZ*NCH*HALF)/256, 256, 0, stream>>>(
        delta, u_bf, x_dbl, A_log, Dp, hin, ycat);

    // out_proj split-K=4: P = ycat @ W^T  (grid 32x16x4 = 2048 blocks)
    gemm128_kernel<0,64,4><<<dim3(NTOK/128, DIMD/64, 4), 256, 0, stream>>>(
        ycat, DINNER, w_out, DINNER, DIMD, nullptr,
        P0, P1, P2o, P3o, nullptr);
    // fused: x2 = sum(P)+x ; ln2_bf = LN(x2)
    reduce_ln4_kernel<<<NTOK, 256, 0, stream>>>(
        P0, P1, P2o, P3o, x, ln2_g, ln2_b, x2, ln2_bf);

    // MLP1: gelu(ln2 @ W1^T + b1) -> bf16 (overwrites out_proj partials - ok)
    gemm128_kernel<2,128,1><<<dim3(NTOK/128, MLPD/128), 256, 0, stream>>>(
        ln2_bf, DIMD, w_m1, DIMD, MLPD, mlp_b1,
        nullptr, nullptr, nullptr, nullptr, mlp_h);

    // MLP2 split-K=4: P = mlp_h @ W2^T ; out = sum(P)+b2+x2
    gemm128_kernel<0,64,4><<<dim3(NTOK/128, DIMD/64, 4), 256, 0, stream>>>(
        mlp_h, MLPD, w_m2, MLPD, DIMD, nullptr,
        P0, P1, P2m, P3m, nullptr);
    reduce4_kernel<<<(NTOK*DIMD)/1024, 256, 0, stream>>>(
        P0, P1, P2m, P3m, mlp_b2, x2, out);
}